// Round 6
// baseline (590.509 us; speedup 1.0000x reference)
//
#include <hip/hip_runtime.h>
#include <cstdint>
#include <cstddef>

// BitLinear inference, round 7: 2-blocks/CU GEMM for epilogue/prologue overlap.
// Round-6 GEMM used 128 KiB LDS -> 1 block/CU -> 512 blocks in 2 sequential
// rounds; every block's 256 KiB f32 epilogue burst (128 MiB aggregate) and
// first-tile prologue ran with the matrix pipe idle. This round: K-tile
// 128 B -> 64 B halves LDS to 64 KiB -> 2 blocks/CU, all 512 blocks
// co-resident; one block's epilogue/barriers overlap the other's MFMA and
// waves/CU doubles to 16. Swizzle re-derived for 64-B rows: read slot
// (ks*32+hi*16) ^ ((row&3)<<4) => 8 bank-groups x 8 lanes = 8-cyc optimum;
// source pre-applies ((l&3)^((l>>2)&3))<<4, LDS dest linear (rule 21).
//
// ws layout (bytes):
//   [0       .. 16)        red[4] = {sum_w, sumabs_w, sum_b, sumabs_b}
//   [1024    .. 132096)    x_scale[32768] f32
//   [132096  .. 1180672)   w_q int8 [1024*1024]
//   [1180672 .. 34735104)  x_q int8 [32768*1024]
//   [34735104.. 34737152)  part[512] f32 (w partials: [0..256) sum,
//                          [256..512) sumabs)

typedef __attribute__((ext_vector_type(4))) int int4v;
typedef __attribute__((ext_vector_type(16))) int int16v;

static constexpr int DIM = 1024;    // inner dim K (bytes per i8 row)
static constexpr int OUTF = 1024;   // output features N
static constexpr int MROWS = 32768; // B*S
static constexpr float INV_WN = 1.0f / (1024.0f * 1024.0f);
static constexpr float INV_BN = 1.0f / 1024.0f;

#define OFF_XSCALE 1024
#define OFF_WQ 132096
#define OFF_XQ 1180672
#define OFF_PART 34735104

__device__ inline float wave_sum(float v) {
#pragma unroll
  for (int off = 32; off; off >>= 1) v += __shfl_xor(v, off);
  return v;
}
__device__ inline float wave_max(float v) {
#pragma unroll
  for (int off = 32; off; off >>= 1) v = fmaxf(v, __shfl_xor(v, off));
  return v;
}

// ---------------------------------------------------------------- reductions
// per-block partials to ws (no atomics, no memset); block 0 also finalizes
// the bias stats (red[2], red[3]).
__global__ __launch_bounds__(256) void reduce_wb(const float* __restrict__ w,
                                                 const float* __restrict__ b,
                                                 float* __restrict__ red,
                                                 float* __restrict__ part) {
  __shared__ float ss[4], sa[4];
  const int t = threadIdx.x;
  const int lane = t & 63, wv = t >> 6;
  float s = 0.0f, a = 0.0f;
  const float4* w4 = (const float4*)w;
  const int idx = blockIdx.x * 256 + t;
#pragma unroll
  for (int i = 0; i < 4; ++i) {
    float4 v = w4[idx + i * 65536];
    s += (v.x + v.y) + (v.z + v.w);
    a += (fabsf(v.x) + fabsf(v.y)) + (fabsf(v.z) + fabsf(v.w));
  }
  s = wave_sum(s);
  a = wave_sum(a);
  if (lane == 0) { ss[wv] = s; sa[wv] = a; }
  __syncthreads();
  if (t == 0) part[blockIdx.x] = (ss[0] + ss[1]) + (ss[2] + ss[3]);
  if (t == 1) part[256 + blockIdx.x] = (sa[0] + sa[1]) + (sa[2] + sa[3]);
  if (blockIdx.x == 0) {
    __syncthreads();  // block-uniform branch, safe
    float4 v = ((const float4*)b)[t];
    float s2 = (v.x + v.y) + (v.z + v.w);
    float a2 = (fabsf(v.x) + fabsf(v.y)) + (fabsf(v.z) + fabsf(v.w));
    s2 = wave_sum(s2);
    a2 = wave_sum(a2);
    if (lane == 0) { ss[wv] = s2; sa[wv] = a2; }
    __syncthreads();
    if (t == 0) {
      red[2] = (ss[0] + ss[1]) + (ss[2] + ss[3]);
      red[3] = (sa[0] + sa[1]) + (sa[2] + sa[3]);
    }
  }
}

// ---------------------------------------------------------------- weight quant
// each block derives wmean from the 256 partials (L2-hit, ~free);
// block 0 finalizes red[0], red[1] for the GEMM epilogue.
__global__ __launch_bounds__(256) void quant_w(const float* __restrict__ w,
                                               const float* __restrict__ part,
                                               float* __restrict__ red,
                                               signed char* __restrict__ wq) {
  __shared__ float smean;
  const int t = threadIdx.x;
  if (t < 64) {  // wave-uniform branch (wave 0)
    float s = 0.0f;
#pragma unroll
    for (int i = 0; i < 4; ++i) s += part[t * 4 + i];
    s = wave_sum(s);
    if (t == 0) smean = s * INV_WN;
    if (blockIdx.x == 0) {
      float a = 0.0f;
#pragma unroll
      for (int i = 0; i < 4; ++i) a += part[256 + t * 4 + i];
      a = wave_sum(a);
      if (t == 0) { red[0] = s; red[1] = a; }
    }
  }
  __syncthreads();
  const float wmean = smean;
  const int idx = blockIdx.x * 256 + t;
  float4 v = ((const float4*)w)[idx];
  int q0, q1, q2, q3;
  float d;
  d = v.x - wmean; q0 = d > 0.f ? 1 : (d < 0.f ? -1 : 0);
  d = v.y - wmean; q1 = d > 0.f ? 1 : (d < 0.f ? -1 : 0);
  d = v.z - wmean; q2 = d > 0.f ? 1 : (d < 0.f ? -1 : 0);
  d = v.w - wmean; q3 = d > 0.f ? 1 : (d < 0.f ? -1 : 0);
  const int pk = (q0 & 0xff) | ((q1 & 0xff) << 8) | ((q2 & 0xff) << 16) | ((q3 & 0xff) << 24);
  ((int*)wq)[idx] = pk;
}

// ---------------------------------------------------------------- activation quant
// one wave per row; 16 floats/lane in registers; no __syncthreads
__global__ __launch_bounds__(256) void quant_x(const float* __restrict__ x,
                                               signed char* __restrict__ xq,
                                               float* __restrict__ xscale) {
  const int wv = threadIdx.x >> 6;
  const int lane = threadIdx.x & 63;
  const int row = blockIdx.x * 4 + wv;
  const float4* xr = (const float4*)(x + (size_t)row * DIM);
  float4 v[4];
  float ss = 0.0f, ma = 0.0f;
#pragma unroll
  for (int it = 0; it < 4; ++it) {
    v[it] = xr[it * 64 + lane];
    ss += v[it].x * v[it].x + v[it].y * v[it].y + v[it].z * v[it].z + v[it].w * v[it].w;
    ma = fmaxf(ma, fmaxf(fmaxf(fabsf(v[it].x), fabsf(v[it].y)),
                         fmaxf(fabsf(v[it].z), fabsf(v[it].w))));
  }
  ss = wave_sum(ss);
  ma = wave_max(ma);

  const float l2 = sqrtf(ss);
  const float inv = 0.03125f / fmaxf(l2, 1e-12f);       // dim_scale / max(l2,eps)
  const float scale = 127.0f / fmaxf(ma * inv, 1e-5f);  // per-token int8 scale
  const float f = inv * scale;

  int* outp = (int*)(xq + (size_t)row * DIM);
#pragma unroll
  for (int it = 0; it < 4; ++it) {
    const int q0 = (int)fminf(fmaxf(rintf(v[it].x * f), -128.f), 127.f);
    const int q1 = (int)fminf(fmaxf(rintf(v[it].y * f), -128.f), 127.f);
    const int q2 = (int)fminf(fmaxf(rintf(v[it].z * f), -128.f), 127.f);
    const int q3 = (int)fminf(fmaxf(rintf(v[it].w * f), -128.f), 127.f);
    outp[it * 64 + lane] =
        (q0 & 0xff) | ((q1 & 0xff) << 8) | ((q2 & 0xff) << 16) | ((q3 & 0xff) << 24);
  }
  if (lane == 0) xscale[row] = scale;
}

// ---------------------------------------------------------------- GEMM (i8)
// 256x256 tile, K-tile = 64 B (2 K-steps of 32), 8 waves (2M x 4N),
// per-wave 128x64 output as 4x2 fragments of 32x32. LDS 64 KiB total
// (As/Bs 2x16 KiB each) -> 2 blocks/CU, all 512 blocks co-resident.
// Per K-tile: COMPUTE(cur) -> vmcnt(0) -> s_barrier -> STAGE next into cur
// (1 barrier/tile). 64-B-row swizzle: read slot (ks*32+hi*16)^((row&3)<<4);
// stage source pre-applies ((l&3)^((l>>2)&3))<<4; LDS dest linear.
__global__ __launch_bounds__(512, 4) void gemm_i8(
    const signed char* __restrict__ Aq,  // [M, K] i8
    const signed char* __restrict__ Wq,  // [N, K] i8
    const float* __restrict__ bias,
    const float* __restrict__ red,
    const float* __restrict__ xscale,
    float* __restrict__ out) {
  __shared__ signed char As[2][256 * 64];  // 2 x 16 KiB
  __shared__ signed char Bs[2][256 * 64];  // 2 x 16 KiB

  const int t = threadIdx.x;
  const int lane = t & 63;
  const int wv = t >> 6;       // 0..7
  const int l31 = lane & 31;
  const int hi = lane >> 5;    // K-half selector for 32x32 fragments
  const int wr = wv >> 2;      // 0..1  M-half of tile
  const int wc = wv & 3;       // 0..3  N-quarter of tile

  // bijective XCD swizzle (512 blocks, 64/XCD); bn fastest inside an XCD so
  // the 4 blocks sharing one A panel (256KB xq) land on the same L2.
  const int orig = blockIdx.x;
  const int swz = (orig & 7) * 64 + (orig >> 3);
  const int bn = swz & 3;
  const int bm = swz >> 2;

  const signed char* Ab = Aq + (size_t)bm * 256 * DIM;
  const signed char* Bb = Wq + (size_t)bn * 256 * DIM;

  // stage geometry: chunk c (0..15) = 16 rows x 64 B; lane l covers
  // row c*16 + (l>>2), 16-B slot l&3. Source pre-applies inverse swizzle.
  const int srow = lane >> 2;                          // row within chunk
  const int swsrc = (((lane & 3) ^ (srow & 3)) << 4);  // inv-swizzled src byte

  int16v acc[4][2] = {};

// stage one 64-B K-tile (tt) of A and B into buffer dd: 4 loads / thread
#define STAGE(tt, dd)                                                            \
  do {                                                                           \
    const size_t koff_ = (size_t)(tt) * 64 + swsrc;                              \
    _Pragma("unroll") for (int i_ = 0; i_ < 2; ++i_) {                           \
      const int c_ = wv * 2 + i_; /* 0..15: 16 rows of 64 B each */              \
      const size_t roff_ = (size_t)(c_ * 16 + srow) * DIM + koff_;               \
      __builtin_amdgcn_global_load_lds(                                          \
          (const __attribute__((address_space(1))) void*)(Ab + roff_),           \
          (__attribute__((address_space(3))) void*)(&As[dd][c_ * 1024 + lane * 16]), \
          16, 0, 0);                                                             \
      __builtin_amdgcn_global_load_lds(                                          \
          (const __attribute__((address_space(1))) void*)(Bb + roff_),           \
          (__attribute__((address_space(3))) void*)(&Bs[dd][c_ * 1024 + lane * 16]), \
          16, 0, 0);                                                             \
    }                                                                            \
  } while (0)

// one K-tile: 4 B-frags + 8 A-frags read once; 16 MFMA (4 mf x 2 nf x 2 ks)
#define COMPUTE(cc)                                                              \
  do {                                                                           \
    const int swr_ = (l31 & 3) << 4; /* row&3 == l31&3 for A and B rows */       \
    int4v bf[2][2];                                                              \
    _Pragma("unroll") for (int nf_ = 0; nf_ < 2; ++nf_) {                        \
      const int r_ = wc * 64 + nf_ * 32 + l31;                                   \
      _Pragma("unroll") for (int ks_ = 0; ks_ < 2; ++ks_)                        \
          bf[nf_][ks_] = *(const int4v*)&Bs[cc][r_ * 64 +                        \
                                                ((ks_ * 32 + hi * 16) ^ swr_)];  \
    }                                                                            \
    _Pragma("unroll") for (int mf_ = 0; mf_ < 4; ++mf_) {                        \
      int4v af[2];                                                               \
      const int r_ = wr * 128 + mf_ * 32 + l31;                                  \
      _Pragma("unroll") for (int ks_ = 0; ks_ < 2; ++ks_)                        \
          af[ks_] = *(const int4v*)&As[cc][r_ * 64 +                             \
                                           ((ks_ * 32 + hi * 16) ^ swr_)];       \
      __builtin_amdgcn_s_setprio(1);                                             \
      _Pragma("unroll") for (int nf_ = 0; nf_ < 2; ++nf_)                        \
          _Pragma("unroll") for (int ks_ = 0; ks_ < 2; ++ks_)                    \
              acc[mf_][nf_] = __builtin_amdgcn_mfma_i32_32x32x32_i8(             \
                  af[ks_], bf[nf_][ks_], acc[mf_][nf_], 0, 0, 0);                \
      __builtin_amdgcn_s_setprio(0);                                             \
    }                                                                            \
  } while (0)

  STAGE(0, 0);
  STAGE(1, 1);
  asm volatile("s_waitcnt vmcnt(4)" ::: "memory");  // own tile-0 loads landed
  asm volatile("s_barrier" ::: "memory");           // everyone's tile-0 landed
#pragma unroll 1
  for (int tp = 0; tp < 8; ++tp) {
    COMPUTE(0);                                      // tile 2tp (buf0)
    asm volatile("s_waitcnt vmcnt(0)" ::: "memory"); // own tile-(2tp+1) landed
    asm volatile("s_barrier" ::: "memory");          // all read buf0; all verified buf1
    if (tp < 7) STAGE(2 * tp + 2, 0);                // refill buf0 (safe)
    COMPUTE(1);                                      // tile 2tp+1 (buf1)
    if (tp < 7) {
      asm volatile("s_waitcnt vmcnt(0)" ::: "memory"); // own tile-(2tp+2) landed
      asm volatile("s_barrier" ::: "memory");          // all read buf1; all verified buf0
      STAGE(2 * tp + 3, 1);                            // refill buf1 (safe)
    }
  }
#undef COMPUTE
#undef STAGE

  // epilogue: ternary bias + dequant
  // C/D layout (32x32): col = lane&31, row = (reg&3) + 8*(reg>>2) + 4*hi
  const float wscale = red[1] * INV_WN;
  const float bscale = red[3] * INV_BN;
  const float bmean = red[2] * INV_BN;
  const float wb = wscale * bscale;

  int bq[2];
#pragma unroll
  for (int nf = 0; nf < 2; ++nf) {
    const float bd = bias[bn * 256 + wc * 64 + nf * 32 + l31] - bmean;
    bq[nf] = bd > 0.f ? 1 : (bd < 0.f ? -1 : 0);
  }

#pragma unroll
  for (int mf = 0; mf < 4; ++mf) {
#pragma unroll
    for (int rq = 0; rq < 4; ++rq) {
      const int mg = bm * 256 + wr * 128 + mf * 32 + rq * 8 + hi * 4;
      const float4 xs = *(const float4*)&xscale[mg];
      float rec[4];
      rec[0] = 1.0f / (wb * xs.x);
      rec[1] = 1.0f / (wb * xs.y);
      rec[2] = 1.0f / (wb * xs.z);
      rec[3] = 1.0f / (wb * xs.w);
#pragma unroll
      for (int nf = 0; nf < 2; ++nf) {
        const int n = bn * 256 + wc * 64 + nf * 32 + l31;
#pragma unroll
        for (int rr = 0; rr < 4; ++rr) {
          const int reg = rq * 4 + rr;  // reg>>2==rq, reg&3==rr
          out[(size_t)(mg + rr) * OUTF + n] =
              (float)(acc[mf][nf][reg] + bq[nf]) * rec[rr];
        }
      }
    }
  }
}

extern "C" void kernel_launch(void* const* d_in, const int* in_sizes, int n_in,
                              void* d_out, int out_size, void* d_ws, size_t ws_size,
                              hipStream_t stream) {
  const float* x = (const float*)d_in[0];
  const float* w = (const float*)d_in[1];
  const float* b = (const float*)d_in[2];
  float* out = (float*)d_out;
  char* ws = (char*)d_ws;

  float* red = (float*)ws;
  float* xscale = (float*)(ws + OFF_XSCALE);
  signed char* wq = (signed char*)(ws + OFF_WQ);
  signed char* xq = (signed char*)(ws + OFF_XQ);
  float* part = (float*)(ws + OFF_PART);

  reduce_wb<<<256, 256, 0, stream>>>(w, b, red, part);
  quant_w<<<1024, 256, 0, stream>>>(w, part, red, wq);
  quant_x<<<MROWS / 4, 256, 0, stream>>>(x, xq, xscale);
  gemm_i8<<<dim3(512), 512, 0, stream>>>(xq, wq, b, red, xscale, out);
}